// Round 16
// 843.319 us; speedup vs baseline: 7.9808x; 1.0249x over previous
//
#include <hip/hip_runtime.h>
#include <hip/hip_bf16.h>

#define NP 100000
#define NL 10000
#define ND 500
#define H 128
#define HH (H * H)
#define E1 2000000
#define E2 500000
#define NOUT 10
#define NCOPY 16
#define NPP (2 * NP)
#define NCNT (NL + ND + 2 * NP)
#define NROW (NL + ND)
#define CHUNK 8192
#define LABHB ((E1 + CHUNK - 1) / CHUNK)
#define DISHB ((E2 + CHUNK - 1) / CHUNK)
#define CNT_BLOCKS ((E1 + E2 + 255) / 256)
#define EMBP ((NP * H + 255) / 256)
#define RED_LAB ((NL + 255) / 256)
#define RED_DIS ((ND + 255) / 256)
#define RED_P ((NPP + 255) / 256)
#define PAT_BLOCKS (NP / 16)

typedef __hip_bfloat16 bf16;
typedef __attribute__((ext_vector_type(8))) short bf16x8;
typedef __attribute__((ext_vector_type(4))) float f32x4;

__device__ __forceinline__ float bfbits2f(unsigned short s) {
    union { unsigned int u; float f; } v;
    v.u = (unsigned int)s << 16;
    return v.f;
}
__device__ __forceinline__ float2 ld_bf2(const bf16* p) {
    unsigned int u = *(const unsigned int*)p;
    return make_float2(bfbits2f((unsigned short)(u & 0xFFFFu)), bfbits2f((unsigned short)(u >> 16)));
}
__device__ __forceinline__ void st_bf2(bf16* p, float2 v) {
    union { unsigned int u; bf16 b[2]; } t;
    t.b[0] = __float2bfloat16(v.x);
    t.b[1] = __float2bfloat16(v.y);
    *(unsigned int*)p = t.u;
}
__device__ __forceinline__ float ldin(const void* p, size_t i, int f32m) {
    return f32m ? ((const float*)p)[i] : __bfloat162float(((const bf16*)p)[i]);
}

// ---------------- input dtype detection ----------------
__global__ void k_detect(const unsigned short* __restrict__ xp, int* __restrict__ flags) {
    int t = threadIdx.x;
    int cnt = 0;
    for (int i = t; i < 4096; i += 256) {
        unsigned short w = xp[2 * i];
        int e = (w >> 7) & 0xFF;
        if (w == 0 || (e >= 114 && e <= 141)) cnt++;
    }
    __shared__ int sh[256];
    sh[t] = cnt;
    __syncthreads();
    for (int s = 128; s > 0; s >>= 1) {
        if (t < s) sh[t] += sh[t + s];
        __syncthreads();
    }
    if (t == 0) flags[0] = (sh[0] < 2048) ? 1 : 0;
}

// ---- merged: p-count | lab/dis hists | hp embed | L1 weight-precompute ----------------
#define PB0 CNT_BLOCKS
#define PB1 (PB0 + LABHB)
#define PB2 (PB1 + DISHB)
#define PB3 (PB2 + EMBP)
#define PB4 (PB3 + 16)
#define PB5 (PB4 + 7)
#define PB6 (PB5 + 64)
__global__ void k_count_embed(const int* __restrict__ e1s, const int* __restrict__ e1d,
                              const int* __restrict__ e2s, const int* __restrict__ e2d,
                              unsigned int* __restrict__ ccnt, unsigned short* __restrict__ r1s,
                              unsigned short* __restrict__ r2s, unsigned int* __restrict__ labHist,
                              unsigned int* __restrict__ disHist, const void* __restrict__ xp,
                              const void* __restrict__ Wp, const void* __restrict__ bp,
                              const void* __restrict__ Wlab, const void* __restrict__ blab,
                              const void* __restrict__ Wdis, const void* __restrict__ bdis,
                              const void* __restrict__ Wl1, const void* __restrict__ bl1,
                              const void* __restrict__ Wr1, bf16* __restrict__ hp,
                              float* __restrict__ WpWl0, float* __restrict__ WpWl1,
                              float* __restrict__ vecs, bf16* __restrict__ w23bT1,
                              const int* __restrict__ flags) {
    __shared__ unsigned int histp[NL / 2];
    int b = blockIdx.x, t = threadIdx.x;
    if (b < PB0) {
        int copy = b & (NCOPY - 1);
        unsigned int* c = ccnt + (size_t)copy * NPP;
        unsigned int tag = (unsigned int)copy << 12;
        int e = b * 256 + t;
        if (e < E1) {
            unsigned int o = atomicAdd(&c[e1s[e]], 1u);
            r1s[e] = (unsigned short)(tag | (o & 0xFFFu));
        } else if (e < E1 + E2) {
            int i = e - E1;
            unsigned int o = atomicAdd(&c[NP + e2s[i]], 1u);
            r2s[i] = (unsigned short)(tag | (o & 0xFFFu));
        }
    } else if (b < PB1) {
        int c = b - PB0;
        for (int i = t; i < NL / 2; i += 256) histp[i] = 0;
        __syncthreads();
        int e0 = c * CHUNK, ee = min(E1, e0 + CHUNK);
        for (int e = e0 + t; e < ee; e += 256) {
            int dd = e1d[e];
            atomicAdd(&histp[dd >> 1], 1u << (16 * (dd & 1)));
        }
        __syncthreads();
        for (int i = t; i < NL; i += 256)
            labHist[(size_t)c * NL + i] = (histp[i >> 1] >> (16 * (i & 1))) & 0xFFFFu;
    } else if (b < PB2) {
        int c = b - PB1;
        for (int i = t; i < ND / 2; i += 256) histp[i] = 0;
        __syncthreads();
        int e0 = c * CHUNK, ee = min(E2, e0 + CHUNK);
        for (int e = e0 + t; e < ee; e += 256) {
            int dd = e2d[e];
            atomicAdd(&histp[dd >> 1], 1u << (16 * (dd & 1)));
        }
        __syncthreads();
        for (int i = t; i < ND; i += 256)
            disHist[(size_t)c * ND + i] = (histp[i >> 1] >> (16 * (i & 1))) & 0xFFFFu;
    } else if (b < PB3) {
        int f32m = flags[0];
        int idx = (b - PB2) * 256 + t;
        int h = idx & 127;
        int i = idx >> 7;
        float acc = ldin(bp, h, f32m);
#pragma unroll
        for (int k = 0; k < 16; ++k)
            acc = fmaf(ldin(xp, (size_t)i * 16 + k, f32m), ldin(Wp, (size_t)k * H + h, f32m), acc);
        hp[idx] = __float2bfloat16(acc);
    } else if (b < PB4) {
        int f32m = flags[0];
        int pb = b - PB3;
        bool first = pb < 8;
        size_t woff = first ? 0 : (size_t)HH;
        float* outp = first ? WpWl0 : WpWl1;
        int k = (first ? pb : pb - 8) * 2 + (t >> 7);
        int h = t & 127;
        float s = 0.f;
        for (int m = 0; m < H; ++m)
            s = fmaf(ldin(Wp, (size_t)k * H + m, f32m), ldin(Wl1, woff + (size_t)m * H + h, f32m), s);
        outp[k * H + h] = s;
    } else if (b < PB5) {
        int f32m = flags[0];
        int idx = (b - PB4) * 256 + t;
        if (idx < 13 * 128) {
            int v = idx >> 7, h = idx & 127;
            float s = 0.f;
            if (v == 12) {
                s = ldin(bl1, 2 * H + h, f32m) + ldin(bl1, 3 * H + h, f32m);
            } else {
                const void* A;
                size_t aoff = 0;
                const void* W;
                size_t woff;
                float add = 0.f;
                switch (v) {
                    case 0: A = Wlab; W = Wl1; woff = 2 * (size_t)HH; break;
                    case 1: A = blab; W = Wl1; woff = 2 * (size_t)HH; break;
                    case 2: A = Wdis; W = Wl1; woff = 3 * (size_t)HH; break;
                    case 3: A = Wdis; aoff = H; W = Wl1; woff = 3 * (size_t)HH; break;
                    case 4: A = bdis; W = Wl1; woff = 3 * (size_t)HH; break;
                    case 5: A = Wlab; W = Wr1; woff = 0; break;
                    case 6: A = blab; W = Wr1; woff = 0; add = ldin(bl1, h, f32m); break;
                    case 7: A = Wdis; W = Wr1; woff = (size_t)HH; break;
                    case 8: A = Wdis; aoff = H; W = Wr1; woff = (size_t)HH; break;
                    case 9: A = bdis; W = Wr1; woff = (size_t)HH; add = ldin(bl1, H + h, f32m); break;
                    case 10: A = bp; W = Wl1; woff = 0; break;
                    default: A = bp; W = Wl1; woff = (size_t)HH; break;
                }
                for (int m = 0; m < H; ++m)
                    s = fmaf(ldin(A, aoff + m, f32m), ldin(W, woff + (size_t)m * H + h, f32m), s);
                s += add;
            }
            vecs[v * 128 + h] = s;
        }
    } else {
        int f32m = flags[0];
        int idx = (b - PB5) * 256 + t;
        if (idx < HH) {
            int k = idx >> 7, n = idx & 127;
            float v = ldin(Wr1, (size_t)2 * HH + idx, f32m) + ldin(Wr1, (size_t)3 * HH + idx, f32m);
            w23bT1[(size_t)n * H + k] = __float2bfloat16(v);
        }
    }
}

// ---- reduce: chunk/copy exclusive bases; totals -> cnt --------------------------------
__global__ void k_reduce(unsigned int* __restrict__ labHist, unsigned int* __restrict__ disHist,
                         unsigned int* __restrict__ ccnt, int* __restrict__ cnt) {
    int b = blockIdx.x, t = threadIdx.x;
    if (b < RED_LAB) {
        int bin = b * 256 + t;
        if (bin < NL) {
            unsigned int run = 0;
            for (int k = 0; k < LABHB; ++k) {
                unsigned int x = labHist[(size_t)k * NL + bin];
                labHist[(size_t)k * NL + bin] = run;
                run += x;
            }
            cnt[bin] = (int)run;
        }
    } else if (b < RED_LAB + RED_DIS) {
        int bin = (b - RED_LAB) * 256 + t;
        if (bin < ND) {
            unsigned int run = 0;
            for (int k = 0; k < DISHB; ++k) {
                unsigned int x = disHist[(size_t)k * ND + bin];
                disHist[(size_t)k * ND + bin] = run;
                run += x;
            }
            cnt[NL + bin] = (int)run;
        }
    } else {
        int bin = (b - RED_LAB - RED_DIS) * 256 + t;
        if (bin < NPP) {
            unsigned int run = 0;
#pragma unroll
            for (int k = 0; k < NCOPY; ++k) {
                unsigned int x = ccnt[(size_t)k * NPP + bin];
                ccnt[(size_t)k * NPP + bin] = run;
                run += x;
            }
            cnt[NL + ND + bin] = (int)run;
        }
    }
}

#define SCAN_ELEMS 2048
__global__ void k_scan1(const int* __restrict__ in, int* __restrict__ out,
                        int* __restrict__ bsums, int n) {
    int t = threadIdx.x;
    int base = blockIdx.x * SCAN_ELEMS + t * 8;
    int v[8], tsum = 0;
#pragma unroll
    for (int j = 0; j < 8; ++j) {
        v[j] = (base + j < n) ? in[base + j] : 0;
        tsum += v[j];
    }
    __shared__ int sh[256];
    sh[t] = tsum;
    __syncthreads();
    for (int d = 1; d < 256; d <<= 1) {
        int x = (t >= d) ? sh[t - d] : 0;
        __syncthreads();
        sh[t] += x;
        __syncthreads();
    }
    int run = sh[t] - tsum;
    if (t == 255) bsums[blockIdx.x] = sh[255];
#pragma unroll
    for (int j = 0; j < 8; ++j) {
        if (base + j < n) out[base + j] = run;
        run += v[j];
    }
}

__global__ void k_scan2(int* __restrict__ bsums, int nb) {
    int t = threadIdx.x;
    int v = (t < nb) ? bsums[t] : 0;
    __shared__ int sh[256];
    sh[t] = v;
    __syncthreads();
    for (int d = 1; d < 256; d <<= 1) {
        int x = (t >= d) ? sh[t - d] : 0;
        __syncthreads();
        sh[t] += x;
        __syncthreads();
    }
    if (t < nb) bsums[t] = sh[t] - v;
}

__global__ void k_scan3(int* __restrict__ out, const int* __restrict__ bsums, int n) {
    int i = blockIdx.x * 256 + threadIdx.x;
    if (i < n) out[i] += bsums[i / SCAN_ELEMS];
}

// ---- fill (+ last block zeros bns: 8 segments) ----------------------------------------
__global__ void k_fill(const int* __restrict__ e1s, const int* __restrict__ e1d,
                       const int* __restrict__ e2s, const int* __restrict__ e2d,
                       const int* __restrict__ off, const unsigned int* __restrict__ ccnt,
                       const unsigned short* __restrict__ r1s,
                       const unsigned short* __restrict__ r2s,
                       const unsigned int* __restrict__ labHist,
                       const unsigned int* __restrict__ disHist, int* __restrict__ nbr,
                       float* __restrict__ bns) {
    __shared__ unsigned int slot[NL];
    int b = blockIdx.x, t = threadIdx.x;
    if (b < CNT_BLOCKS) {
        int e = b * 256 + t;
        if (e < E1) {
            int ss = e1s[e];
            int r = r1s[e];
            int base = (int)ccnt[(size_t)(r >> 12) * NPP + ss];
            nbr[off[NL + ND + ss] + base + (r & 0xFFF)] = e1d[e];
        } else if (e < E1 + E2) {
            int i = e - E1;
            int ss = e2s[i];
            int r = r2s[i];
            int base = (int)ccnt[(size_t)(r >> 12) * NPP + NP + ss];
            nbr[off[NL + ND + NP + ss] + base + (r & 0xFFF)] = e2d[i];
        }
    } else if (b < CNT_BLOCKS + LABHB) {
        int c = b - CNT_BLOCKS;
        for (int i = t; i < NL; i += 256)
            slot[i] = (unsigned int)off[i] + labHist[(size_t)c * NL + i];
        __syncthreads();
        int e0 = c * CHUNK, ee = min(E1, e0 + CHUNK);
        for (int e = e0 + t; e < ee; e += 256) {
            unsigned int pos = atomicAdd(&slot[e1d[e]], 1u);
            nbr[pos] = e1s[e];
        }
    } else if (b < CNT_BLOCKS + LABHB + DISHB) {
        int c = b - CNT_BLOCKS - LABHB;
        for (int i = t; i < ND; i += 256)
            slot[i] = (unsigned int)off[NL + i] + disHist[(size_t)c * ND + i];
        __syncthreads();
        int e0 = c * CHUNK, ee = min(E2, e0 + CHUNK);
        for (int e = e0 + t; e < ee; e += 256) {
            unsigned int pos = atomicAdd(&slot[e2d[e]], 1u);
            nbr[pos] = e2s[e];
        }
    } else {
        for (int i = t; i < 8 * H; i += 256) bns[i] = 0.f;
    }
}

// ---------------- L1 stage1: gather 16-dim mean of x_p per lab/dis row ------------------
__global__ void k_stage1_L1(const void* __restrict__ xp, const int* __restrict__ off,
                            const int* __restrict__ cnt, const int* __restrict__ nbr,
                            float* __restrict__ mxp, const int* __restrict__ flags) {
    int f32m = flags[0];
    int t = threadIdx.x;
    int w = t >> 6, lane = t & 63;
    int row = blockIdx.x * 4 + w;
    if (row >= NROW) return;
    int s0 = off[row], c = cnt[row];
    int slot = lane >> 4, dim = lane & 15;
    float a0 = 0.f, a1 = 0.f, a2 = 0.f, a3 = 0.f;
    int j = slot;
    for (; j + 16 <= c; j += 16) {
        a0 += ldin(xp, (size_t)nbr[s0 + j] * 16 + dim, f32m);
        a1 += ldin(xp, (size_t)nbr[s0 + j + 4] * 16 + dim, f32m);
        a2 += ldin(xp, (size_t)nbr[s0 + j + 8] * 16 + dim, f32m);
        a3 += ldin(xp, (size_t)nbr[s0 + j + 12] * 16 + dim, f32m);
    }
    for (; j < c; j += 4) a0 += ldin(xp, (size_t)nbr[s0 + j] * 16 + dim, f32m);
    float acc = (a0 + a1) + (a2 + a3);
    acc += __shfl_xor(acc, 16);
    acc += __shfl_xor(acc, 32);
    if (lane < 16) mxp[(size_t)row * 16 + lane] = acc / fmaxf((float)c, 1.f);
}

// -------- L1 patmm: scalar gathers + MFMA | lab/dis affine | per-block stats ------------
#define LD1_BLOCKS ((NROW + 1) / 2)
#define HPAD 136
#define APAD 132
__global__ void k_patmm_L1(const bf16* __restrict__ hp, const void* __restrict__ xl,
                           const void* __restrict__ xd, const int* __restrict__ off,
                           const int* __restrict__ cnt, const int* __restrict__ nbr,
                           const bf16* __restrict__ w23bT1, const float* __restrict__ vecs,
                           const float* __restrict__ WpWl0, const float* __restrict__ WpWl1,
                           const float* __restrict__ mxp, bf16* __restrict__ aggp,
                           float* __restrict__ bufL, float* __restrict__ bufD,
                           float* __restrict__ blocksums, const int* __restrict__ flags) {
    int t = threadIdx.x;
    int f32m = flags[0];
    if (blockIdx.x < PAT_BLOCKS) {
        __shared__ bf16 hpA[16][HPAD];
        __shared__ float accf[16][APAD];
        __shared__ float svec[6][128];
        __shared__ float s_mxl[16], s_onL[16], s_d0[16], s_d1[16], s_onD[16];
        int w = t >> 6, lane = t & 63;
        int p0 = blockIdx.x * 16;
        {
            const unsigned int* hpu = (const unsigned int*)(hp + (size_t)p0 * H);
            for (int i = t; i < 16 * 64; i += 256) {
                int r = i >> 6, c = i & 63;
                *(unsigned int*)&hpA[r][2 * c] = hpu[(size_t)r * 64 + c];
            }
        }
        {
            const int map[6] = {0, 1, 2, 3, 4, 12};
            for (int i = t; i < 6 * 128; i += 256)
                svec[i >> 7][i & 127] = vecs[map[i >> 7] * 128 + (i & 127)];
        }
        {
            int g = t >> 4, sl = t & 15;
            int p = p0 + g;
            int s1 = off[NL + ND + p], c1 = cnt[NL + ND + p];
            float a = 0.f;
            for (int j = sl; j < c1; j += 16) a += ldin(xl, nbr[s1 + j], f32m);
            a += __shfl_xor(a, 1);
            a += __shfl_xor(a, 2);
            a += __shfl_xor(a, 4);
            a += __shfl_xor(a, 8);
            int s2 = off[NL + ND + NP + p], c2 = cnt[NL + ND + NP + p];
            float d0 = 0.f, d1 = 0.f;
            for (int j = sl; j < c2; j += 16) {
                int q = nbr[s2 + j];
                d0 += ldin(xd, (size_t)2 * q, f32m);
                d1 += ldin(xd, (size_t)2 * q + 1, f32m);
            }
            d0 += __shfl_xor(d0, 1); d0 += __shfl_xor(d0, 2);
            d0 += __shfl_xor(d0, 4); d0 += __shfl_xor(d0, 8);
            d1 += __shfl_xor(d1, 1); d1 += __shfl_xor(d1, 2);
            d1 += __shfl_xor(d1, 4); d1 += __shfl_xor(d1, 8);
            if (sl == 0) {
                s_mxl[g] = a / fmaxf((float)c1, 1.f);
                s_onL[g] = (c1 > 0) ? 1.f : 0.f;
                s_d0[g] = d0 / fmaxf((float)c2, 1.f);
                s_d1[g] = d1 / fmaxf((float)c2, 1.f);
                s_onD[g] = (c2 > 0) ? 1.f : 0.f;
            }
        }
        __syncthreads();
        {
            int m = lane & 15, kg = lane >> 4;
            bf16x8 afr[4];
#pragma unroll
            for (int ks = 0; ks < 4; ++ks)
                afr[ks] = *(const bf16x8*)&hpA[m][ks * 32 + kg * 8];
            int n0 = w * 32;
#pragma unroll
            for (int tt = 0; tt < 2; ++tt) {
                int nc = n0 + tt * 16 + m;
                f32x4 acc = {0.f, 0.f, 0.f, 0.f};
#pragma unroll
                for (int ks = 0; ks < 4; ++ks) {
                    bf16x8 bfr = *(const bf16x8*)&w23bT1[(size_t)nc * H + ks * 32 + kg * 8];
                    acc = __builtin_amdgcn_mfma_f32_16x16x32_bf16(afr[ks], bfr, acc, 0, 0, 0);
                }
#pragma unroll
                for (int rg = 0; rg < 4; ++rg)
                    accf[kg * 4 + rg][nc] = acc[rg];
            }
        }
        __syncthreads();
        for (int i = t; i < 16 * 64; i += 256) {
            int r = i >> 6, cc = (i & 63) * 2;
            float l0 = s_onL[r] * fmaf(s_mxl[r], svec[0][cc], svec[1][cc]);
            float l1 = s_onL[r] * fmaf(s_mxl[r], svec[0][cc + 1], svec[1][cc + 1]);
            float q0 = s_onD[r] * (s_d0[r] * svec[2][cc] + s_d1[r] * svec[3][cc] + svec[4][cc]);
            float q1 = s_onD[r] * (s_d0[r] * svec[2][cc + 1] + s_d1[r] * svec[3][cc + 1] + svec[4][cc + 1]);
            float v0 = accf[r][cc] + l0 + q0 + svec[5][cc];
            float v1 = accf[r][cc + 1] + l1 + q1 + svec[5][cc + 1];
            accf[r][cc] = v0;
            accf[r][cc + 1] = v1;
            st_bf2(aggp + (size_t)(p0 + r) * H + cc, make_float2(v0, v1));
        }
        __syncthreads();
        if (t < 128) {
            float s = 0.f, q = 0.f;
#pragma unroll
            for (int r = 0; r < 16; ++r) {
                float v = accf[r][t];
                s += v;
                q = fmaf(v, v, q);
            }
            blocksums[(size_t)blockIdx.x * 256 + t] = s;
            blocksums[(size_t)blockIdx.x * 256 + 128 + t] = q;
        }
    } else {
        int bb = blockIdx.x - PAT_BLOCKS;
        int rr = bb * 2 + (t >> 7);
        int h = t & 127;
        if (rr >= NROW) return;
        if (rr < NL) {
            float acc = vecs[6 * 128 + h] + ldin(xl, rr, f32m) * vecs[5 * 128 + h];
            if (cnt[rr] > 0) {
                float s = vecs[10 * 128 + h];
                const float* mx = mxp + (size_t)rr * 16;
#pragma unroll
                for (int k = 0; k < 16; ++k) s = fmaf(mx[k], WpWl0[k * H + h], s);
                acc += s;
            }
            bufL[(size_t)rr * H + h] = acc;
        } else {
            int rd = rr - NL;
            float acc = vecs[9 * 128 + h] + ldin(xd, (size_t)2 * rd, f32m) * vecs[7 * 128 + h] +
                        ldin(xd, (size_t)2 * rd + 1, f32m) * vecs[8 * 128 + h];
            if (cnt[rr] > 0) {
                float s = vecs[11 * 128 + h];
                const float* mx = mxp + (size_t)rr * 16;
#pragma unroll
                for (int k = 0; k < 16; ++k) s = fmaf(mx[k], WpWl1[k * H + h], s);
                acc += s;
            }
            bufD[(size_t)rd * H + h] = acc;
        }
    }
}

// -------- bnred: patient stats from blocksums (+ lab/dis stats when grid>64) -----------
__global__ void k_bnred(const float* __restrict__ blocksums, const float* __restrict__ bufL,
                        const float* __restrict__ bufD, float* __restrict__ sums) {
    int b = blockIdx.x, t = threadIdx.x;
    if (b < 64) {
        float acc = 0.f;
        for (int r = b; r < PAT_BLOCKS; r += 64) acc += blocksums[(size_t)r * 256 + t];
        atomicAdd(&sums[t], acc);
        return;
    }
    int h = t & 127;
    int sub = t >> 7;
    float s = 0.f, s2 = 0.f;
    float* sm;
    if (b < 320) {
        int bid = b - 64;
        for (int i = bid * 2 + sub; i < NL; i += 512) {
            float v = bufL[(size_t)i * H + h];
            s += v;
            s2 = fmaf(v, v, s2);
        }
        sm = sums + 2 * H;
    } else {
        int bid = b - 320;
        for (int i = bid * 2 + sub; i < ND; i += 128) {
            float v = bufD[(size_t)i * H + h];
            s += v;
            s2 = fmaf(v, v, s2);
        }
        sm = sums + 4 * H;
    }
    __shared__ float ls[256], ls2[256];
    ls[t] = s;
    ls2[t] = s2;
    __syncthreads();
    if (sub == 0) {
        atomicAdd(&sm[h], s + ls[128 + h]);
        atomicAdd(&sm[H + h], s2 + ls2[128 + h]);
    }
}

// ---- L2 stage1: mm_small (L1 lab/dis BN inline) + prep23 -------------------------------
#define S2_MM 1313
#define S2_PREP 64
#define S2_TOTAL (S2_MM + S2_PREP)
__global__ void k_stage1_L2(const float* __restrict__ bufL, const float* __restrict__ bufD,
                            const float* __restrict__ bns, const void* __restrict__ bng1,
                            const void* __restrict__ bnb1, const void* __restrict__ Wl,
                            bf16* __restrict__ tlp, bf16* __restrict__ tdp,
                            const void* __restrict__ Wr, const void* __restrict__ bl,
                            bf16* __restrict__ w23bT, float* __restrict__ b23,
                            const int* __restrict__ flags) {
    __shared__ float smm[8][H];
    int b = blockIdx.x, t = threadIdx.x;
    int f32m = flags[0];
    if (b < S2_MM) {
        int bb = b;
        bool lab = bb < 1250;
        const float* buf = lab ? bufL : bufD;
        int N = lab ? NL : ND;
        float invN = lab ? 1.f / NL : 1.f / ND;
        int so = lab ? 2 * H : 4 * H;
        int go = lab ? H : 2 * H;
        bf16* outp = lab ? tlp : tdp;
        size_t woff = lab ? (size_t)2 * HH : (size_t)3 * HH;
        int r0 = (lab ? bb : bb - 1250) * 8;
        int h = t & 127, half = t >> 7;
        // BN constants for this thread's fixed column h
        float m = bns[so + h] * invN;
        float v = fmaf(-m, m, bns[so + H + h] * invN);
        float sc = rsqrtf(v + 1e-5f) * ldin(bng1, go + h, f32m);
        float be = ldin(bnb1, go + h, f32m);
        for (int r = half; r < 8; r += 2) {
            int ri = r0 + r;
            float x = (ri < N) ? buf[(size_t)ri * H + h] : 0.f;
            smm[r][h] = (ri < N) ? fmaxf(fmaf(x - m, sc, be), 0.f) : 0.f;
        }
        __syncthreads();
        int rb = half * 4;
        float a0 = 0.f, a1 = 0.f, a2 = 0.f, a3 = 0.f;
        for (int k = 0; k < H; ++k) {
            float wv = ldin(Wl, woff + (size_t)k * H + h, f32m);
            a0 = fmaf(smm[rb + 0][k], wv, a0);
            a1 = fmaf(smm[rb + 1][k], wv, a1);
            a2 = fmaf(smm[rb + 2][k], wv, a2);
            a3 = fmaf(smm[rb + 3][k], wv, a3);
        }
        float acc[4] = {a0, a1, a2, a3};
#pragma unroll
        for (int r = 0; r < 4; ++r)
            if (r0 + rb + r < N)
                outp[(size_t)(r0 + rb + r) * H + h] = __float2bfloat16(acc[r]);
    } else {
        int pb = b - S2_MM;
        int idx = pb * 256 + t;
        if (idx < HH) {
            int k = idx >> 7, n = idx & 127;
            float v = ldin(Wr, (size_t)2 * HH + idx, f32m) + ldin(Wr, (size_t)3 * HH + idx, f32m);
            w23bT[(size_t)n * H + k] = __float2bfloat16(v);
        }
        if (idx < H)
            b23[idx] = ldin(bl, (size_t)2 * H + idx, f32m) + ldin(bl, (size_t)3 * H + idx, f32m);
    }
}

// -------- L2 patmm: in-place aggp update (L1 pat BN inline) + per-block stats -----------
__global__ void k_patmm_L2(bf16* __restrict__ aggp, const bf16* __restrict__ tlp,
                           const bf16* __restrict__ tdp, const int* __restrict__ off,
                           const int* __restrict__ cnt, const int* __restrict__ nbr,
                           const bf16* __restrict__ w23bT, const float* __restrict__ b23,
                           const float* __restrict__ bns, const void* __restrict__ bng1,
                           const void* __restrict__ bnb1, float* __restrict__ blocksums,
                           const int* __restrict__ flags) {
    __shared__ bf16 hpA[16][HPAD];
    __shared__ float accf[16][APAD];
    int t = threadIdx.x;
    int f32m = flags[0];
    int w = t >> 6, lane = t & 63, c0 = 2 * lane;
    int p0 = blockIdx.x * 16;
    // stage aggp rows with inline L1 patient BN+ReLU (column fixed per thread: i&63 == t&63)
    {
        int cc = (t & 63) * 2;
        const float invN = 1.f / NP;
        float m0 = bns[cc] * invN, m1 = bns[cc + 1] * invN;
        float v0 = fmaf(-m0, m0, bns[128 + cc] * invN);
        float v1 = fmaf(-m1, m1, bns[128 + cc + 1] * invN);
        float sc0 = rsqrtf(v0 + 1e-5f) * ldin(bng1, cc, f32m);
        float sc1 = rsqrtf(v1 + 1e-5f) * ldin(bng1, cc + 1, f32m);
        float be0 = ldin(bnb1, cc, f32m), be1 = ldin(bnb1, cc + 1, f32m);
        for (int i = t; i < 16 * 64; i += 256) {
            int r = i >> 6;
            float2 v = ld_bf2(aggp + (size_t)(p0 + r) * H + cc);
            st_bf2(&hpA[r][cc], make_float2(fmaxf(fmaf(v.x - m0, sc0, be0), 0.f),
                                            fmaxf(fmaf(v.y - m1, sc1, be1), 0.f)));
        }
    }
    {
        const int* off1 = off + NL + ND;
        const int* cnt1 = cnt + NL + ND;
        const int* off2 = off + NL + ND + NP;
        const int* cnt2 = cnt + NL + ND + NP;
        float2 bb = *(const float2*)(b23 + c0);
#pragma unroll
        for (int r = 0; r < 4; ++r) {
            int p = p0 + w * 4 + r;
            int s1 = off1[p], c1 = cnt1[p];
            const int* nb1 = nbr + s1;
            float2 aa[4];
#pragma unroll
            for (int u = 0; u < 4; ++u) aa[u] = make_float2(0.f, 0.f);
            int j = 0;
            for (; j + 4 <= c1; j += 4) {
#pragma unroll
                for (int u = 0; u < 4; ++u) {
                    float2 v = ld_bf2(tlp + (size_t)nb1[j + u] * H + c0);
                    aa[u].x += v.x;
                    aa[u].y += v.y;
                }
            }
            for (; j < c1; ++j) {
                float2 v = ld_bf2(tlp + (size_t)nb1[j] * H + c0);
                aa[0].x += v.x;
                aa[0].y += v.y;
            }
            float a1x = (aa[0].x + aa[1].x) + (aa[2].x + aa[3].x);
            float a1y = (aa[0].y + aa[1].y) + (aa[2].y + aa[3].y);
            int s2 = off2[p], c2 = cnt2[p];
            const int* nb2 = nbr + s2;
            float2 a2a = make_float2(0.f, 0.f), a2b = a2a;
            j = 0;
            for (; j + 2 <= c2; j += 2) {
                float2 va = ld_bf2(tdp + (size_t)nb2[j] * H + c0);
                float2 vb = ld_bf2(tdp + (size_t)nb2[j + 1] * H + c0);
                a2a.x += va.x; a2a.y += va.y;
                a2b.x += vb.x; a2b.y += vb.y;
            }
            if (j < c2) {
                float2 v = ld_bf2(tdp + (size_t)nb2[j] * H + c0);
                a2a.x += v.x;
                a2a.y += v.y;
            }
            float i1 = 1.f / fmaxf((float)c1, 1.f), i2 = 1.f / fmaxf((float)c2, 1.f);
            accf[w * 4 + r][c0] = a1x * i1 + (a2a.x + a2b.x) * i2 + bb.x;
            accf[w * 4 + r][c0 + 1] = a1y * i1 + (a2a.y + a2b.y) * i2 + bb.y;
        }
    }
    __syncthreads();
    {
        int m = lane & 15, kg = lane >> 4;
        bf16x8 afr[4];
#pragma unroll
        for (int ks = 0; ks < 4; ++ks)
            afr[ks] = *(const bf16x8*)&hpA[m][ks * 32 + kg * 8];
        int n0 = w * 32;
#pragma unroll
        for (int tt = 0; tt < 2; ++tt) {
            int nc = n0 + tt * 16 + m;
            f32x4 acc = {0.f, 0.f, 0.f, 0.f};
#pragma unroll
            for (int ks = 0; ks < 4; ++ks) {
                bf16x8 bfr = *(const bf16x8*)&w23bT[(size_t)nc * H + ks * 32 + kg * 8];
                acc = __builtin_amdgcn_mfma_f32_16x16x32_bf16(afr[ks], bfr, acc, 0, 0, 0);
            }
#pragma unroll
            for (int rg = 0; rg < 4; ++rg)
                accf[kg * 4 + rg][nc] += acc[rg];
        }
    }
    __syncthreads();
    for (int i = t; i < 16 * 64; i += 256) {
        int r = i >> 6, cc = (i & 63) * 2;
        st_bf2(aggp + (size_t)(p0 + r) * H + cc, make_float2(accf[r][cc], accf[r][cc + 1]));
    }
    if (t < 128) {
        float s = 0.f, q = 0.f;
#pragma unroll
        for (int r = 0; r < 16; ++r) {
            float v = accf[r][t];
            s += v;
            q = fmaf(v, v, q);
        }
        blocksums[(size_t)blockIdx.x * 256 + t] = s;
        blocksums[(size_t)blockIdx.x * 256 + 128 + t] = q;
    }
}

// ---------------- head with fused L2 patient BN+ReLU ----------------
__global__ void k_head(const bf16* __restrict__ aggp, const float* __restrict__ sums,
                       const void* __restrict__ bng, const void* __restrict__ bnb,
                       const void* __restrict__ W1, const void* __restrict__ b1,
                       const void* __restrict__ W2, const void* __restrict__ b2f,
                       void* __restrict__ out, const int* __restrict__ flags) {
    int f32m = flags[0];
    __shared__ float W1s[H * 64];
    __shared__ float W2s[64 * NOUT];
    __shared__ float b1s[64], b2s[NOUT];
    __shared__ float rows[16][H];
    __shared__ float h1s[16][65];
    __shared__ float lgs[16][16];
    int t = threadIdx.x;
    for (int i = t; i < H * 64; i += 256) W1s[i] = ldin(W1, i, f32m);
    for (int i = t; i < 64 * NOUT; i += 256) W2s[i] = ldin(W2, i, f32m);
    if (t < 64) b1s[t] = ldin(b1, t, f32m);
    else if (t >= 64 && t < 64 + NOUT) b2s[t - 64] = ldin(b2f, t - 64, f32m);
    int p0 = blockIdx.x * 16;
    {
        int cc = (t & 63) * 2;
        const float invN = 1.f / NP;
        float m0 = sums[cc] * invN, m1 = sums[cc + 1] * invN;
        float v0 = fmaf(-m0, m0, sums[128 + cc] * invN);
        float v1 = fmaf(-m1, m1, sums[128 + cc + 1] * invN);
        float sc0 = rsqrtf(v0 + 1e-5f) * ldin(bng, cc, f32m);
        float sc1 = rsqrtf(v1 + 1e-5f) * ldin(bng, cc + 1, f32m);
        float be0 = ldin(bnb, cc, f32m), be1 = ldin(bnb, cc + 1, f32m);
        for (int i = t; i < 16 * 64; i += 256) {
            int r = i >> 6;
            float2 v = ld_bf2(aggp + (size_t)(p0 + r) * H + cc);
            rows[r][cc] = fmaxf(fmaf(v.x - m0, sc0, be0), 0.f);
            rows[r][cc + 1] = fmaxf(fmaf(v.y - m1, sc1, be1), 0.f);
        }
    }
    __syncthreads();
    int w = t >> 6, lane = t & 63;
    const float* r0 = rows[4 * w + 0];
    const float* r1 = rows[4 * w + 1];
    const float* r2 = rows[4 * w + 2];
    const float* r3 = rows[4 * w + 3];
    float a0 = b1s[lane], a1 = a0, a2 = a0, a3 = a0;
#pragma unroll 4
    for (int k = 0; k < H; ++k) {
        float wv = W1s[k * 64 + lane];
        a0 = fmaf(r0[k], wv, a0);
        a1 = fmaf(r1[k], wv, a1);
        a2 = fmaf(r2[k], wv, a2);
        a3 = fmaf(r3[k], wv, a3);
    }
    h1s[4 * w + 0][lane] = fmaxf(a0, 0.f);
    h1s[4 * w + 1][lane] = fmaxf(a1, 0.f);
    h1s[4 * w + 2][lane] = fmaxf(a2, 0.f);
    h1s[4 * w + 3][lane] = fmaxf(a3, 0.f);
    __syncthreads();
    int pat = lane >> 4, oidx = lane & 15;
    int prow = 4 * w + pat;
    float lg = 0.f;
    if (oidx < NOUT) {
        lg = b2s[oidx];
        const float* hh = h1s[prow];
#pragma unroll 8
        for (int k = 0; k < 64; ++k) lg = fmaf(hh[k], W2s[k * NOUT + oidx], lg);
        lgs[prow][oidx] = lg;
    }
    __syncthreads();
    if (oidx < NOUT) {
        float m = -1e30f;
#pragma unroll
        for (int k = 0; k < NOUT; ++k) m = fmaxf(m, lgs[prow][k]);
        float s = 0.f;
#pragma unroll
        for (int k = 0; k < NOUT; ++k) s += __expf(lgs[prow][k] - m);
        float r = lg - m - __logf(s);
        if (f32m)
            ((float*)out)[(size_t)(p0 + prow) * NOUT + oidx] = r;
        else
            ((bf16*)out)[(size_t)(p0 + prow) * NOUT + oidx] = __float2bfloat16(r);
    }
}

extern "C" void kernel_launch(void* const* d_in, const int* in_sizes, int n_in, void* d_out,
                              int out_size, void* d_ws, size_t ws_size, hipStream_t stream) {
    const int* e1s = (const int*)d_in[23];
    const int* e1d = (const int*)d_in[24];
    const int* e2s = (const int*)d_in[25];
    const int* e2d = (const int*)d_in[26];
    const int NPOOL = 2 * (E1 + E2);

    char* wsb = (char*)d_ws;
    size_t o = 0;
    auto af = [&](size_t nwords) { void* p = wsb + o * 4; o += nwords; return p; };
    int* flags = (int*)af(16);
    bf16* w23bT = (bf16*)af(HH / 2);
    bf16* w23bT1 = (bf16*)af(HH / 2);
    float* b23 = (float*)af(H);
    float* bns = (float*)af(8 * H);
    int* bsums = (int*)af(256);
    float* WpWl0 = (float*)af(16 * H);
    float* WpWl1 = (float*)af(16 * H);
    float* vecs = (float*)af(13 * 128);
    int* cnt = (int*)af(NCNT);
    int* off = (int*)af(NCNT);
    int* nbr = (int*)af(NPOOL);
    bf16* hp = (bf16*)af((size_t)NP * H / 2);
    size_t arena = o;
    unsigned short* r1s = (unsigned short*)af(E1 / 2);
    unsigned short* r2s = (unsigned short*)af(E2 / 2);
    unsigned int* ccnt = (unsigned int*)af((size_t)NCOPY * NPP);
    unsigned int* labHist = (unsigned int*)af((size_t)LABHB * NL);
    unsigned int* disHist = (unsigned int*)af((size_t)DISHB * ND);
    size_t endA = o;
    o = arena;
    float* bufL = (float*)af((size_t)NL * H);
    float* bufD = (float*)af((size_t)ND * H);
    bf16* tlp = (bf16*)af((size_t)NL * H / 2);
    bf16* tdp = (bf16*)af((size_t)ND * H / 2);
    bf16* aggp = (bf16*)af((size_t)NP * H / 2);
    float* mxp = (float*)af((size_t)NROW * 16);
    float* blocksums = (float*)af((size_t)PAT_BLOCKS * 256);
    size_t endB = o;
    o = endA > endB ? endA : endB;
    (void)ws_size;

    k_detect<<<1, 256, 0, stream>>>((const unsigned short*)d_in[0], flags);

    hipMemsetAsync(ccnt, 0, (size_t)NCOPY * NPP * 4, stream);
    k_count_embed<<<PB6, 256, 0, stream>>>(e1s, e1d, e2s, e2d, ccnt, r1s, r2s, labHist, disHist,
                                           d_in[0], d_in[3], d_in[4], d_in[5], d_in[6], d_in[7],
                                           d_in[8], d_in[9], d_in[10], d_in[11], hp, WpWl0,
                                           WpWl1, vecs, w23bT1, flags);
    k_reduce<<<RED_LAB + RED_DIS + RED_P, 256, 0, stream>>>(labHist, disHist, ccnt, cnt);
    int nb = (NCNT + SCAN_ELEMS - 1) / SCAN_ELEMS;
    k_scan1<<<nb, 256, 0, stream>>>(cnt, off, bsums, NCNT);
    k_scan2<<<1, 256, 0, stream>>>(bsums, nb);
    k_scan3<<<(NCNT + 255) / 256, 256, 0, stream>>>(off, bsums, NCNT);
    k_fill<<<CNT_BLOCKS + LABHB + DISHB + 1, 256, 0, stream>>>(e1s, e1d, e2s, e2d, off, ccnt,
                                                               r1s, r2s, labHist, disHist, nbr,
                                                               bns);

    // ---- layer 1 (algebraically collapsed) ----
    k_stage1_L1<<<(NROW + 3) / 4, 256, 0, stream>>>(d_in[0], off, cnt, nbr, mxp, flags);
    k_patmm_L1<<<PAT_BLOCKS + LD1_BLOCKS, 256, 0, stream>>>(hp, d_in[1], d_in[2], off, cnt, nbr,
                                                            w23bT1, vecs, WpWl0, WpWl1, mxp,
                                                            aggp, bufL, bufD, blocksums, flags);
    k_bnred<<<384, 256, 0, stream>>>(blocksums, bufL, bufD, bns);

    // ---- layer 2: all BN applications fused into consumers ----
    k_stage1_L2<<<S2_TOTAL, 256, 0, stream>>>(bufL, bufD, bns, d_in[15], d_in[16], d_in[12],
                                              tlp, tdp, d_in[14], d_in[13], w23bT, b23, flags);
    k_patmm_L2<<<PAT_BLOCKS, 256, 0, stream>>>(aggp, tlp, tdp, off, cnt, nbr, w23bT, b23, bns,
                                               d_in[15], d_in[16], blocksums, flags);
    k_bnred<<<64, 256, 0, stream>>>(blocksums, bufL, bufD, bns + 6 * H);
    k_head<<<NP / 16, 256, 0, stream>>>(aggp, bns + 6 * H, d_in[17], d_in[18], d_in[19],
                                        d_in[20], d_in[21], d_in[22], d_out, flags);
}